// Round 2
// baseline (97.857 us; speedup 1.0000x reference)
//
#include <hip/hip_runtime.h>
#include <hip/hip_bf16.h>
#include <math.h>

// out[n,:] = s1 .* FWHT( (u/4096) .* FWHT( s2 .* x[n,:] ) ),
// u = g_mu + softplus(g_rho)*epsilon, FWHT unnormalized Walsh-Hadamard.
// Radix-64: D = 4096 = 64*64. One wave (64 lanes) per row, 64 floats/lane.
// Four in-register fwht64 passes + two LDS 64x64 transposes (XOR-swizzled,
// conflict-free). No inter-wave synchronization at all.

#define WHVI_D 4096

__device__ __forceinline__ void fwht64(float v[64]) {
#pragma unroll
    for (int s = 1; s < 64; s <<= 1) {
#pragma unroll
        for (int i = 0; i < 64; ++i) {
            if ((i & s) == 0) {
                float a = v[i];
                float b = v[i | s];
                v[i] = a + b;
                v[i | s] = a - b;
            }
        }
    }
}

__global__ __launch_bounds__(256)
void u_precompute_kernel(const float* __restrict__ g_mu,
                         const float* __restrict__ g_rho,
                         const float* __restrict__ g_eps,
                         float* __restrict__ u) {
    int i = blockIdx.x * 256 + threadIdx.x;  // grid covers exactly 4096
    float rho = g_rho[i];
    float sp = fmaxf(rho, 0.0f) + __logf(1.0f + __expf(-fabsf(rho)));
    u[i] = (g_mu[i] + sp * g_eps[i]) * (1.0f / 4096.0f);
}

// Swizzled LDS word address for logical element (h = high base-64 digit,
// l = low base-64 digit):  A(h,l) = h*64 + (((l>>2) ^ (h&15)) << 2) + (l&3).
// - contiguous-in-l runs of 4 stay contiguous & 16B-aligned  -> b128 ops
// - b128 phase: float4-bank-group = (c ^ (h&7)) -> all 8 groups evenly hit
// - b32 strided access (h varies per instr, l = lane): bijective onto 64
//   consecutive words -> 2 lanes/bank, free.

template <bool UINLINE>
__global__ __launch_bounds__(64)
void whvi64_kernel(const float* __restrict__ x,
                   const float* __restrict__ s1,
                   const float* __restrict__ s2,
                   const float* __restrict__ u,
                   const float* __restrict__ g_mu,
                   const float* __restrict__ g_rho,
                   const float* __restrict__ g_eps,
                   float* __restrict__ out,
                   int nrows) {
    __shared__ float lds[WHVI_D];

    const int l = threadIdx.x;   // 0..63 : lane owns high-digit h=l initially
    const int row = blockIdx.x;
    if (row >= nrows) return;

    float v[64];

    // ---- load x[row, l*64 + 0..63], scale by s2 (b128, per-lane contiguous) ----
    {
        const float4* xv = reinterpret_cast<const float4*>(x + (size_t)row * WHVI_D + l * 64);
        const float4* sv = reinterpret_cast<const float4*>(s2 + l * 64);
#pragma unroll
        for (int c = 0; c < 16; ++c) {
            float4 a = xv[c];
            float4 s = sv[c];
            v[4 * c + 0] = a.x * s.x;
            v[4 * c + 1] = a.y * s.y;
            v[4 * c + 2] = a.z * s.z;
            v[4 * c + 3] = a.w * s.w;
        }
    }

    // ---- pass 1: transform low digit d0 (regs) ----
    fwht64(v);

    // ---- transpose 1: write rows (b128 swizzled), read columns (b32) ----
#pragma unroll
    for (int c = 0; c < 16; ++c) {
        int a4 = l * 16 + (c ^ (l & 15));
        *reinterpret_cast<float4*>(&lds[a4 << 2]) =
            make_float4(v[4 * c + 0], v[4 * c + 1], v[4 * c + 2], v[4 * c + 3]);
    }
    __syncthreads();  // single-wave wg: compiles to a waitcnt, ~free
#pragma unroll
    for (int r = 0; r < 64; ++r) {
        int addr = r * 64 + ((((l >> 2) ^ (r & 15)) << 2) | (l & 3));
        v[r] = lds[addr];
    }

    // ---- pass 2: transform high digit d1 -> FWHT#1 done.
    //      lane l, reg r  =  y[r*64 + l] ----
    fwht64(v);

    // ---- diagonal u (1/4096 folded in); index r*64+l is lane-coalesced ----
    if (UINLINE) {
#pragma unroll
        for (int r = 0; r < 64; ++r) {
            int idx = r * 64 + l;
            float rho = g_rho[idx];
            float sp = fmaxf(rho, 0.0f) + __logf(1.0f + __expf(-fabsf(rho)));
            float uu = (g_mu[idx] + sp * g_eps[idx]) * (1.0f / 4096.0f);
            v[r] *= uu;
        }
    } else {
#pragma unroll
        for (int r = 0; r < 64; ++r) v[r] *= u[r * 64 + l];
    }

    // ---- pass 3: FWHT#2 on the digit already in regs (e1) ----
    fwht64(v);

    // ---- transpose 2: write columns (b32 swizzled), read rows (b128) ----
    __syncthreads();
#pragma unroll
    for (int r = 0; r < 64; ++r) {
        int addr = r * 64 + ((((l >> 2) ^ (r & 15)) << 2) | (l & 3));
        lds[addr] = v[r];
    }
    __syncthreads();
#pragma unroll
    for (int c = 0; c < 16; ++c) {
        int a4 = l * 16 + (c ^ (l & 15));
        float4 t = *reinterpret_cast<const float4*>(&lds[a4 << 2]);
        v[4 * c + 0] = t.x;
        v[4 * c + 1] = t.y;
        v[4 * c + 2] = t.z;
        v[4 * c + 3] = t.w;
    }

    // ---- pass 4: transform e0 -> done. lane l, reg r = out[row, l*64+r] ----
    fwht64(v);

    // ---- s1 scale + store (b128, per-lane contiguous) ----
    {
        const float4* sv = reinterpret_cast<const float4*>(s1 + l * 64);
        float4* ov = reinterpret_cast<float4*>(out + (size_t)row * WHVI_D + l * 64);
#pragma unroll
        for (int c = 0; c < 16; ++c) {
            float4 s = sv[c];
            ov[c] = make_float4(v[4 * c + 0] * s.x, v[4 * c + 1] * s.y,
                                v[4 * c + 2] * s.z, v[4 * c + 3] * s.w);
        }
    }
}

extern "C" void kernel_launch(void* const* d_in, const int* in_sizes, int n_in,
                              void* d_out, int out_size, void* d_ws, size_t ws_size,
                              hipStream_t stream) {
    const float* x     = (const float*)d_in[0];
    const float* s1    = (const float*)d_in[1];
    const float* s2    = (const float*)d_in[2];
    const float* g_mu  = (const float*)d_in[3];
    const float* g_rho = (const float*)d_in[4];
    const float* g_eps = (const float*)d_in[5];
    // d_in[6] is H — unused; the FWHT realizes it exactly.
    float* out = (float*)d_out;

    const int nrows = in_sizes[0] / WHVI_D;  // 8192

    if (ws_size >= WHVI_D * sizeof(float)) {
        float* u = (float*)d_ws;
        u_precompute_kernel<<<WHVI_D / 256, 256, 0, stream>>>(g_mu, g_rho, g_eps, u);
        whvi64_kernel<false><<<nrows, 64, 0, stream>>>(
            x, s1, s2, u, nullptr, nullptr, nullptr, out, nrows);
    } else {
        whvi64_kernel<true><<<nrows, 64, 0, stream>>>(
            x, s1, s2, nullptr, g_mu, g_rho, g_eps, out, nrows);
    }
}